// Round 8
// baseline (707.241 us; speedup 1.0000x reference)
//
#include <hip/hip_runtime.h>
#include <hip/hip_bf16.h>
#include <stdint.h>

// Problem constants (fixed by reference)
#define TSEQ   2048
#define DMODEL 1024
#define NH     16
#define HDIM   64
#define NKVH   4

typedef __attribute__((ext_vector_type(8))) short short8;
typedef __attribute__((ext_vector_type(4))) float f32x4;
typedef __hip_bfloat16 bf16;

// priority comparator: higher score wins; tie -> lower index wins (matches jax top_k)
__device__ __forceinline__ bool pgt(float as, int ai, float bs, int bi) {
    return (as > bs) || (as == bs && ai < bi);
}

// full bitonic sort across 64 lanes, ascending by priority (validated R6/R7)
__device__ __forceinline__ void bsort(float& s, int& i, int lane) {
#pragma unroll
    for (int k = 2; k <= 64; k <<= 1) {
#pragma unroll
        for (int j = k >> 1; j > 0; j >>= 1) {
            float os = __shfl_xor(s, j, 64);
            int   oi = __shfl_xor(i, j, 64);
            bool lower = (lane & j) == 0;
            bool asc   = (lane & k) == 0;
            bool wmin  = (lower == asc);
            bool takeo = (pgt(s, i, os, oi) == wmin);
            if (takeo) { s = os; i = oi; }
        }
    }
}

// bitonic -> ascending cleanup (6 stages) (validated R6/R7)
__device__ __forceinline__ void bmerge(float& s, int& i, int lane) {
#pragma unroll
    for (int j = 32; j > 0; j >>= 1) {
        float os = __shfl_xor(s, j, 64);
        int   oi = __shfl_xor(i, j, 64);
        bool lower = (lane & j) == 0;
        bool takeo = (pgt(s, i, os, oi) == lower);
        if (takeo) { s = os; i = oi; }
    }
}

// selection update: identical semantics to R7's in-loop code. noinline to
// keep one copy in I-cache (called 16x per chunk per wave).
__device__ __attribute__((noinline)) void sel_update(
    float& cs, int& ci, float s, int jb, int lane, bool init)
{
    if (init) {
        cs = s; ci = jb + lane;
        bsort(cs, ci, lane);
        return;
    }
    float th = __shfl(cs, 0, 64);           // 64th-largest so far
    if (__any(s >= th)) {
        float nsv = s; int niv = jb + lane;
        bsort(nsv, niv, lane);
        float rsv = __shfl_xor(nsv, 63, 64);   // descending view
        int   riv = __shfl_xor(niv, 63, 64);
        if (pgt(rsv, riv, cs, ci)) { cs = rsv; ci = riv; }
        bmerge(cs, ci, lane);                  // restore ascending
    }
}

// ---- fp32 -> bf16 conversion of x, wq, wkv, wo ----
__global__ __launch_bounds__(256) void convert_bf16(
    const float* __restrict__ x, const float* __restrict__ wq,
    const float* __restrict__ wkv, const float* __restrict__ wo,
    bf16* __restrict__ cx, bf16* __restrict__ cwq,
    bf16* __restrict__ cwkv, bf16* __restrict__ cwo)
{
    const size_t i0 = (size_t)blockIdx.x * 256 + threadIdx.x;
    const size_t stride = (size_t)gridDim.x * 256;
    for (size_t i = i0; i < 2097152; i += stride) cx[i]   = __float2bfloat16(x[i]);
    for (size_t i = i0; i < 1048576; i += stride) cwq[i]  = __float2bfloat16(wq[i]);
    for (size_t i = i0; i < 524288;  i += stride) cwkv[i] = __float2bfloat16(wkv[i]);
    for (size_t i = i0; i < 1048576; i += stride) cwo[i]  = __float2bfloat16(wo[i]);
}

// ---- MFMA GEMM: C[M,N] fp32 = A[M,K](bf16) @ B[K,N](bf16) + bias[N](fp32)
// 64x64 tile, 4 waves, mfma 16x16x32. (validated R7)
__global__ __launch_bounds__(256) void gemm_bias(
    const bf16* __restrict__ A, const bf16* __restrict__ B,
    const float* __restrict__ bias, float* __restrict__ C,
    int M, int N, int K)
{
    __shared__ short As[64][32];   // (m, k)
    __shared__ short Bt[64][32];   // (n, k)
    const int tid = threadIdx.x;
    const int m0 = blockIdx.y * 64, n0 = blockIdx.x * 64;
    const int w = tid >> 6, lane = tid & 63;
    const int q = lane >> 4, mm = lane & 15;
    f32x4 acc[4];
#pragma unroll
    for (int nb = 0; nb < 4; ++nb) acc[nb] = (f32x4){0.f, 0.f, 0.f, 0.f};
    const int arow = tid >> 2, akc = (tid & 3) * 8;
    const int brow = tid >> 3, bnc = (tid & 7) * 8;
    const short* Ag = (const short*)A;
    const short* Bg = (const short*)B;
    for (int k0 = 0; k0 < K; k0 += 32) {
        __syncthreads();
        short8 av = *(const short8*)(Ag + (size_t)(m0 + arow) * K + k0 + akc);
        *(short8*)(&As[arow][akc]) = av;
        short8 bv = *(const short8*)(Bg + (size_t)(k0 + brow) * N + n0 + bnc);
#pragma unroll
        for (int jj = 0; jj < 8; ++jj) Bt[bnc + jj][brow] = bv[jj];
        __syncthreads();
        short8 af = *(const short8*)(&As[w * 16 + mm][q * 8]);
#pragma unroll
        for (int nb = 0; nb < 4; ++nb) {
            short8 bfr = *(const short8*)(&Bt[nb * 16 + mm][q * 8]);
            acc[nb] = __builtin_amdgcn_mfma_f32_16x16x32_bf16(af, bfr, acc[nb], 0, 0, 0);
        }
    }
#pragma unroll
    for (int nb = 0; nb < 4; ++nb) {
#pragma unroll
        for (int r = 0; r < 4; ++r) {
            int row = m0 + w * 16 + q * 4 + r;
            int col = n0 + nb * 16 + mm;
            C[(size_t)row * N + col] = acc[nb][r] + bias[col];
        }
    }
}

// ---- RMSNorm q and k -> bf16 tiles; V stays fp32 ----
// qbf: (T, H*64) bf16 (NOT pre-scaled; scale applied after MFMA)
// kbf: (kvh, T, 64) bf16 row-major
__global__ __launch_bounds__(256) void norm_kernel(
    const float* __restrict__ qbuf, const float* __restrict__ kvbuf,
    const float* __restrict__ qn_w, const float* __restrict__ kn_w,
    bf16* __restrict__ qbf, bf16* __restrict__ kbf, float* __restrict__ vbuf)
{
    const int t = blockIdx.x;
    const int tid = threadIdx.x;
#pragma unroll
    for (int it = 0; it < 6; ++it) {
        int idx = it * 256 + tid;
        int chunk = idx >> 6;        // 0..15 q heads, 16..19 k kvh, 20..23 v kvh
        int d = idx & 63;
        float val;
        if (chunk < 16)      val = qbuf[(size_t)t * DMODEL + chunk * 64 + d];
        else if (chunk < 20) val = kvbuf[(size_t)t * 512 + (chunk - 16) * 64 + d];
        else                 val = kvbuf[(size_t)t * 512 + 256 + (chunk - 20) * 64 + d];
        if (chunk < 20) {
            float ss = val * val;
#pragma unroll
            for (int j = 32; j > 0; j >>= 1) ss += __shfl_xor(ss, j, 64);
            float rs = 1.0f / sqrtf(ss * (1.0f / 64.0f) + 1e-8f);
            if (chunk < 16) {
                qbf[(size_t)t * DMODEL + chunk * 64 + d] =
                    __float2bfloat16(val * rs * qn_w[d]);
            } else {
                int kvh = chunk - 16;
                kbf[((size_t)kvh * TSEQ + t) * HDIM + d] =
                    __float2bfloat16(val * rs * kn_w[d]);
            }
        } else {
            int kvh = chunk - 20;
            vbuf[((size_t)kvh * TSEQ + t) * HDIM + d] = val;
        }
    }
}

// ---- MFMA-scored fused attention ----
// block = 256 thr / 4 waves = one head x 64 queries (t0..t0+63).
// Per K-chunk (64 keys): stage K to LDS, each wave MFMAs its 16 queries'
// scores (8x mfma_16x16x32), applies ALiBi+causal in C-layout, round-trips
// through LDS (stride 68 -> 2-way banks, free) to lane-per-key order, then
// runs the R7-proven gate + bitonic top-64 per query. Epilogue per query:
// wave softmax + V gather (R7 code).
__global__ __launch_bounds__(256) void attn_kernel(
    const bf16* __restrict__ qbf, const bf16* __restrict__ kbf,
    const float* __restrict__ vbuf, bf16* __restrict__ ybuf)
{
    __shared__ short Qs[64][64];
    __shared__ short Ks[64][64];
    __shared__ float Ss[64][68];
    const int tid = threadIdx.x;
    const int w = tid >> 6, lane = tid & 63;
    const int h = blockIdx.x & 15;
    const int qb = 31 - (blockIdx.x >> 4);   // heavy blocks (large qb) first
    const int kvh = h >> 2;
    const int t0 = qb * 64;
    const float slope = exp2f(-(((float)h / 15.0f) * 8.0f));
    const int mm = lane & 15, quad = lane >> 4;

    // stage Q tile (64 x 64 bf16)
#pragma unroll
    for (int it = 0; it < 2; ++it) {
        int idx = it * 256 + tid;
        int row = idx >> 3, seg = idx & 7;
        *(short8*)(&Qs[row][seg * 8]) =
            *(const short8*)((const short*)qbf + (size_t)(t0 + row) * DMODEL + h * 64 + seg * 8);
    }
    __syncthreads();
    // A-frags fixed for whole kernel: wave w -> q rows [16w, 16w+16)
    short8 af0 = *(const short8*)(&Qs[w * 16 + mm][quad * 8]);
    short8 af1 = *(const short8*)(&Qs[w * 16 + mm][32 + quad * 8]);

    float cs[16]; int ci[16];

    const short* kg = (const short*)kbf + (size_t)kvh * TSEQ * HDIM;
    for (int c = qb; c >= 0; --c) {
        const int jb = c << 6;
        __syncthreads();   // prior Ks reads done
#pragma unroll
        for (int it = 0; it < 2; ++it) {
            int idx = it * 256 + tid;
            int row = idx >> 3, seg = idx & 7;
            *(short8*)(&Ks[row][seg * 8]) =
                *(const short8*)(kg + (size_t)(jb + row) * HDIM + seg * 8);
        }
        __syncthreads();
        // scores: 16 queries x 64 keys per wave
#pragma unroll
        for (int kb = 0; kb < 4; ++kb) {
            short8 b0 = *(const short8*)(&Ks[kb * 16 + mm][quad * 8]);
            short8 b1 = *(const short8*)(&Ks[kb * 16 + mm][32 + quad * 8]);
            f32x4 acc = (f32x4){0.f, 0.f, 0.f, 0.f};
            acc = __builtin_amdgcn_mfma_f32_16x16x32_bf16(af0, b0, acc, 0, 0, 0);
            acc = __builtin_amdgcn_mfma_f32_16x16x32_bf16(af1, b1, acc, 0, 0, 0);
            int col = kb * 16 + mm;
            int jj = jb + col;
#pragma unroll
            for (int r = 0; r < 4; ++r) {
                int qq = w * 16 + quad * 4 + r;
                int tt = t0 + qq;
                float s = (jj <= tt) ? (acc[r] * 0.125f - slope * (float)(tt - jj))
                                     : -1e30f;
                Ss[qq][col] = s;
            }
        }
        // selection for my 16 queries (rows are wave-private; ds deps ordered)
        bool init = (c == qb);
#pragma unroll
        for (int i = 0; i < 16; ++i) {
            float s = Ss[w * 16 + i][lane];
            sel_update(cs[i], ci[i], s, jb, lane, init);
        }
    }
    // epilogue: softmax + V gather per query (R7 code)
    const float* vb = vbuf + (size_t)kvh * TSEQ * HDIM + lane;
#pragma unroll
    for (int i = 0; i < 16; ++i) {
        float c_s = cs[i]; int c_i = ci[i];
        float msx = __shfl(c_s, 63, 64);
        bool valid = c_s > -1e29f;
        float p = valid ? __expf(c_s - msx) : 0.f;
        float l = p;
#pragma unroll
        for (int j2 = 32; j2 > 0; j2 >>= 1) l += __shfl_xor(l, j2, 64);
        float wgt = p / l;
        int widx = valid ? c_i : 0;
        float acc = 0.f;
#pragma unroll 8
        for (int u = 0; u < 64; ++u) {
            float ww = __shfl(wgt, u, 64);
            int  ix = __shfl(widx, u, 64);
            acc += ww * vb[(size_t)ix * HDIM];
        }
        int tt = t0 + w * 16 + i;
        ybuf[(size_t)tt * DMODEL + h * 64 + lane] = __float2bfloat16(acc);
    }
}

extern "C" void kernel_launch(void* const* d_in, const int* in_sizes, int n_in,
                              void* d_out, int out_size, void* d_ws, size_t ws_size,
                              hipStream_t stream)
{
    // d_in order: x, wq, bq, wkv, bkv, wo, bo, qn_w, kn_w  (all fp32)
    const float* x    = (const float*)d_in[0];
    const float* wq   = (const float*)d_in[1];
    const float* bq   = (const float*)d_in[2];
    const float* wkv  = (const float*)d_in[3];
    const float* bkv  = (const float*)d_in[4];
    const float* wo   = (const float*)d_in[5];
    const float* bo   = (const float*)d_in[6];
    const float* qn_w = (const float*)d_in[7];
    const float* kn_w = (const float*)d_in[8];
    char* ws = (char*)d_ws;
    // ws layout (28 MB):
    // cx bf16 4M @0 | cwq 2M @4M | cwkv 1M @6M | cwo 2M @7M |
    // qbuf fp32 8M @9M (reused as ybuf bf16 after norm) | kvbuf fp32 4M @17M |
    // qbf bf16 4M @21M | kbf bf16 1M @25M | vbuf fp32 2M @26M
    bf16*  cx    = (bf16*)(ws);
    bf16*  cwq   = (bf16*)(ws + ((size_t)4  << 20));
    bf16*  cwkv  = (bf16*)(ws + ((size_t)6  << 20));
    bf16*  cwo   = (bf16*)(ws + ((size_t)7  << 20));
    float* qbuf  = (float*)(ws + ((size_t)9  << 20));
    bf16*  ybuf  = (bf16*)(ws + ((size_t)9  << 20));   // aliases qbuf (dead after norm)
    float* kvbuf = (float*)(ws + ((size_t)17 << 20));
    bf16*  qbf   = (bf16*)(ws + ((size_t)21 << 20));
    bf16*  kbf   = (bf16*)(ws + ((size_t)25 << 20));
    float* vbuf  = (float*)(ws + ((size_t)26 << 20));
    float* out   = (float*)d_out;   // fp32 output

    convert_bf16<<<2048, 256, 0, stream>>>(x, wq, wkv, wo, cx, cwq, cwkv, cwo);
    gemm_bias<<<dim3(DMODEL / 64, TSEQ / 64), 256, 0, stream>>>(
        cx, cwq, bq, qbuf, TSEQ, DMODEL, DMODEL);
    gemm_bias<<<dim3(512 / 64, TSEQ / 64), 256, 0, stream>>>(
        cx, cwkv, bkv, kvbuf, TSEQ, 512, DMODEL);
    norm_kernel<<<TSEQ, 256, 0, stream>>>(qbuf, kvbuf, qn_w, kn_w, qbf, kbf, vbuf);
    attn_kernel<<<NH * (TSEQ / 64), 256, 0, stream>>>(qbf, kbf, vbuf, ybuf);
    gemm_bias<<<dim3(DMODEL / 64, TSEQ / 64), 256, 0, stream>>>(
        ybuf, cwo, bo, out, TSEQ, DMODEL, DMODEL);
}

// Round 9
// 583.481 us; speedup vs baseline: 1.2121x; 1.2121x over previous
//
#include <hip/hip_runtime.h>
#include <hip/hip_bf16.h>
#include <stdint.h>

// Problem constants (fixed by reference)
#define TSEQ   2048
#define DMODEL 1024
#define NH     16
#define HDIM   64
#define NKVH   4

typedef __attribute__((ext_vector_type(8))) short short8;
typedef __attribute__((ext_vector_type(4))) float f32x4;
typedef __hip_bfloat16 bf16;

// priority comparator: higher score wins; tie -> lower index wins (matches jax top_k)
__device__ __forceinline__ bool pgt(float as, int ai, float bs, int bi) {
    return (as > bs) || (as == bs && ai < bi);
}

// full bitonic sort across 64 lanes, ascending by priority (validated R6/R7)
__device__ __forceinline__ void bsort(float& s, int& i, int lane) {
#pragma unroll
    for (int k = 2; k <= 64; k <<= 1) {
#pragma unroll
        for (int j = k >> 1; j > 0; j >>= 1) {
            float os = __shfl_xor(s, j, 64);
            int   oi = __shfl_xor(i, j, 64);
            bool lower = (lane & j) == 0;
            bool asc   = (lane & k) == 0;
            bool wmin  = (lower == asc);
            bool takeo = (pgt(s, i, os, oi) == wmin);
            if (takeo) { s = os; i = oi; }
        }
    }
}

// bitonic -> ascending cleanup (6 stages) (validated R6/R7)
__device__ __forceinline__ void bmerge(float& s, int& i, int lane) {
#pragma unroll
    for (int j = 32; j > 0; j >>= 1) {
        float os = __shfl_xor(s, j, 64);
        int   oi = __shfl_xor(i, j, 64);
        bool lower = (lane & j) == 0;
        bool takeo = (pgt(s, i, os, oi) == lower);
        if (takeo) { s = os; i = oi; }
    }
}

struct Sel { float s; int i; };

// merge one unsorted 64-candidate chunk into the sorted kept set.
// noinline (single I-cache copy) but BY VALUE: state stays in VGPRs.
__device__ __attribute__((noinline)) Sel merge_sel(Sel cur, float s, int j, int lane) {
    float nsv = s; int niv = j;
    bsort(nsv, niv, lane);
    float rsv = __shfl_xor(nsv, 63, 64);   // descending view of new chunk
    int   riv = __shfl_xor(niv, 63, 64);
    if (pgt(rsv, riv, cur.s, cur.i)) { cur.s = rsv; cur.i = riv; }
    bmerge(cur.s, cur.i, lane);            // restore ascending
    return cur;
}

// ---- fp32 -> bf16 conversion of x, wq, wkv, wo ----
__global__ __launch_bounds__(256) void convert_bf16(
    const float* __restrict__ x, const float* __restrict__ wq,
    const float* __restrict__ wkv, const float* __restrict__ wo,
    bf16* __restrict__ cx, bf16* __restrict__ cwq,
    bf16* __restrict__ cwkv, bf16* __restrict__ cwo)
{
    const size_t i0 = (size_t)blockIdx.x * 256 + threadIdx.x;
    const size_t stride = (size_t)gridDim.x * 256;
    for (size_t i = i0; i < 2097152; i += stride) cx[i]   = __float2bfloat16(x[i]);
    for (size_t i = i0; i < 1048576; i += stride) cwq[i]  = __float2bfloat16(wq[i]);
    for (size_t i = i0; i < 524288;  i += stride) cwkv[i] = __float2bfloat16(wkv[i]);
    for (size_t i = i0; i < 1048576; i += stride) cwo[i]  = __float2bfloat16(wo[i]);
}

// ---- MFMA GEMM: C[M,N] fp32 = A[M,K](bf16) @ B[K,N](bf16) + bias[N](fp32)
// 64x64 tile, 4 waves, mfma 16x16x32. (validated R7)
__global__ __launch_bounds__(256) void gemm_bias(
    const bf16* __restrict__ A, const bf16* __restrict__ B,
    const float* __restrict__ bias, float* __restrict__ C,
    int M, int N, int K)
{
    __shared__ short As[64][32];   // (m, k)
    __shared__ short Bt[64][32];   // (n, k)
    const int tid = threadIdx.x;
    const int m0 = blockIdx.y * 64, n0 = blockIdx.x * 64;
    const int w = tid >> 6, lane = tid & 63;
    const int q = lane >> 4, mm = lane & 15;
    f32x4 acc[4];
#pragma unroll
    for (int nb = 0; nb < 4; ++nb) acc[nb] = (f32x4){0.f, 0.f, 0.f, 0.f};
    const int arow = tid >> 2, akc = (tid & 3) * 8;
    const int brow = tid >> 3, bnc = (tid & 7) * 8;
    const short* Ag = (const short*)A;
    const short* Bg = (const short*)B;
    for (int k0 = 0; k0 < K; k0 += 32) {
        __syncthreads();
        short8 av = *(const short8*)(Ag + (size_t)(m0 + arow) * K + k0 + akc);
        *(short8*)(&As[arow][akc]) = av;
        short8 bv = *(const short8*)(Bg + (size_t)(k0 + brow) * N + n0 + bnc);
#pragma unroll
        for (int jj = 0; jj < 8; ++jj) Bt[bnc + jj][brow] = bv[jj];
        __syncthreads();
        short8 af = *(const short8*)(&As[w * 16 + mm][q * 8]);
#pragma unroll
        for (int nb = 0; nb < 4; ++nb) {
            short8 bfr = *(const short8*)(&Bt[nb * 16 + mm][q * 8]);
            acc[nb] = __builtin_amdgcn_mfma_f32_16x16x32_bf16(af, bfr, acc[nb], 0, 0, 0);
        }
    }
#pragma unroll
    for (int nb = 0; nb < 4; ++nb) {
#pragma unroll
        for (int r = 0; r < 4; ++r) {
            int row = m0 + w * 16 + q * 4 + r;
            int col = n0 + nb * 16 + mm;
            C[(size_t)row * N + col] = acc[nb][r] + bias[col];
        }
    }
}

// ---- RMSNorm q and k -> bf16 tiles; V stays fp32 ---- (validated R8)
// qbf: (T, H*64) bf16; kbf: (kvh, T, 64) bf16 row-major
__global__ __launch_bounds__(256) void norm_kernel(
    const float* __restrict__ qbuf, const float* __restrict__ kvbuf,
    const float* __restrict__ qn_w, const float* __restrict__ kn_w,
    bf16* __restrict__ qbf, bf16* __restrict__ kbf, float* __restrict__ vbuf)
{
    const int t = blockIdx.x;
    const int tid = threadIdx.x;
#pragma unroll
    for (int it = 0; it < 6; ++it) {
        int idx = it * 256 + tid;
        int chunk = idx >> 6;        // 0..15 q heads, 16..19 k kvh, 20..23 v kvh
        int d = idx & 63;
        float val;
        if (chunk < 16)      val = qbuf[(size_t)t * DMODEL + chunk * 64 + d];
        else if (chunk < 20) val = kvbuf[(size_t)t * 512 + (chunk - 16) * 64 + d];
        else                 val = kvbuf[(size_t)t * 512 + 256 + (chunk - 20) * 64 + d];
        if (chunk < 20) {
            float ss = val * val;
#pragma unroll
            for (int j = 32; j > 0; j >>= 1) ss += __shfl_xor(ss, j, 64);
            float rs = 1.0f / sqrtf(ss * (1.0f / 64.0f) + 1e-8f);
            if (chunk < 16) {
                qbf[(size_t)t * DMODEL + chunk * 64 + d] =
                    __float2bfloat16(val * rs * qn_w[d]);
            } else {
                int kvh = chunk - 16;
                kbf[((size_t)kvh * TSEQ + t) * HDIM + d] =
                    __float2bfloat16(val * rs * kn_w[d]);
            }
        } else {
            int kvh = chunk - 20;
            vbuf[((size_t)kvh * TSEQ + t) * HDIM + d] = val;
        }
    }
}

// ---- MFMA-scored fused attention, one wave per (h, 16 queries) ----
// Barrier-free: A/B fragments loaded straight from global in MFMA order
// (L1/L2-served), scores transposed through a tiny wave-private LDS tile
// (stride 68 -> 2-way banks = free), selection state in registers.
__global__ __launch_bounds__(64) void attn_kernel(
    const bf16* __restrict__ qbf, const bf16* __restrict__ kbf,
    const float* __restrict__ vbuf, bf16* __restrict__ ybuf)
{
    __shared__ float Ss[16][68];
    const int lane = threadIdx.x;
    const int h  = blockIdx.x & 15;
    const int qt = 127 - (blockIdx.x >> 4);   // heavy tiles dispatch first
    const int t0 = qt * 16;
    const int kvh = h >> 2;
    const float slope = exp2f(-(((float)h / 15.0f) * 8.0f));
    const int mm = lane & 15, quad = lane >> 4;

    // A-frags: Q[m = t0+mm][k = quad*8 ..] halves k0=0,32 (gemm-proven layout)
    const short* qg = (const short*)qbf + (size_t)h * 64;
    short8 af0 = *(const short8*)(qg + (size_t)(t0 + mm) * DMODEL + quad * 8);
    short8 af1 = *(const short8*)(qg + (size_t)(t0 + mm) * DMODEL + 32 + quad * 8);

    const short* kg = (const short*)kbf + (size_t)kvh * TSEQ * HDIM;

    float cs[16]; int ci[16];
    const int cmax = (t0 + 15) >> 6;
    for (int c = cmax; c >= 0; --c) {
        const int jb = c << 6;
        // scores for 16 queries x 64 keys: 4 key-blocks of 16
#pragma unroll
        for (int kb = 0; kb < 4; ++kb) {
            const short* kr = kg + (size_t)(jb + kb * 16 + mm) * HDIM;
            short8 b0 = *(const short8*)(kr + quad * 8);
            short8 b1 = *(const short8*)(kr + 32 + quad * 8);
            f32x4 acc = (f32x4){0.f, 0.f, 0.f, 0.f};
            acc = __builtin_amdgcn_mfma_f32_16x16x32_bf16(af0, b0, acc, 0, 0, 0);
            acc = __builtin_amdgcn_mfma_f32_16x16x32_bf16(af1, b1, acc, 0, 0, 0);
            const int jj = jb + kb * 16 + mm;
#pragma unroll
            for (int r = 0; r < 4; ++r) {
                int qq = quad * 4 + r;
                int tt = t0 + qq;
                float s = (jj <= tt) ? (acc[r] * 0.125f - slope * (float)(tt - jj))
                                     : -1e30f;
                Ss[qq][kb * 16 + mm] = s;
            }
        }
        // selection per query (state in registers; merge body one shared copy)
        if (c == cmax) {
#pragma unroll
            for (int i = 0; i < 16; ++i) {
                cs[i] = Ss[i][lane]; ci[i] = jb + lane;
                bsort(cs[i], ci[i], lane);
            }
        } else {
#pragma unroll
            for (int i = 0; i < 16; ++i) {
                float s = Ss[i][lane];
                float th = __shfl(cs[i], 0, 64);   // current 64th-largest
                if (__any(s >= th)) {
                    Sel st{cs[i], ci[i]};
                    st = merge_sel(st, s, jb + lane, lane);
                    cs[i] = st.s; ci[i] = st.i;
                }
            }
        }
    }
    // epilogue: softmax + V gather per query (R7-proven)
    const float* vb = vbuf + (size_t)kvh * TSEQ * HDIM + lane;
#pragma unroll
    for (int i = 0; i < 16; ++i) {
        float c_s = cs[i]; int c_i = ci[i];
        float msx = __shfl(c_s, 63, 64);
        bool valid = c_s > -1e29f;
        float p = valid ? __expf(c_s - msx) : 0.f;
        float l = p;
#pragma unroll
        for (int j2 = 32; j2 > 0; j2 >>= 1) l += __shfl_xor(l, j2, 64);
        float wgt = p / l;
        int widx = valid ? c_i : 0;
        float acc = 0.f;
#pragma unroll 8
        for (int u = 0; u < 64; ++u) {
            float ww = __shfl(wgt, u, 64);
            int  ix = __shfl(widx, u, 64);
            acc += ww * vb[(size_t)ix * HDIM];
        }
        int tt = t0 + i;
        ybuf[(size_t)tt * DMODEL + h * 64 + lane] = __float2bfloat16(acc);
    }
}

extern "C" void kernel_launch(void* const* d_in, const int* in_sizes, int n_in,
                              void* d_out, int out_size, void* d_ws, size_t ws_size,
                              hipStream_t stream)
{
    // d_in order: x, wq, bq, wkv, bkv, wo, bo, qn_w, kn_w  (all fp32)
    const float* x    = (const float*)d_in[0];
    const float* wq   = (const float*)d_in[1];
    const float* bq   = (const float*)d_in[2];
    const float* wkv  = (const float*)d_in[3];
    const float* bkv  = (const float*)d_in[4];
    const float* wo   = (const float*)d_in[5];
    const float* bo   = (const float*)d_in[6];
    const float* qn_w = (const float*)d_in[7];
    const float* kn_w = (const float*)d_in[8];
    char* ws = (char*)d_ws;
    // ws layout (28 MB):
    // cx bf16 4M @0 | cwq 2M @4M | cwkv 1M @6M | cwo 2M @7M |
    // qbuf fp32 8M @9M (reused as ybuf bf16 after norm) | kvbuf fp32 4M @17M |
    // qbf bf16 4M @21M | kbf bf16 1M @25M | vbuf fp32 2M @26M
    bf16*  cx    = (bf16*)(ws);
    bf16*  cwq   = (bf16*)(ws + ((size_t)4  << 20));
    bf16*  cwkv  = (bf16*)(ws + ((size_t)6  << 20));
    bf16*  cwo   = (bf16*)(ws + ((size_t)7  << 20));
    float* qbuf  = (float*)(ws + ((size_t)9  << 20));
    bf16*  ybuf  = (bf16*)(ws + ((size_t)9  << 20));   // aliases qbuf (dead after norm)
    float* kvbuf = (float*)(ws + ((size_t)17 << 20));
    bf16*  qbf   = (bf16*)(ws + ((size_t)21 << 20));
    bf16*  kbf   = (bf16*)(ws + ((size_t)25 << 20));
    float* vbuf  = (float*)(ws + ((size_t)26 << 20));
    float* out   = (float*)d_out;   // fp32 output

    convert_bf16<<<2048, 256, 0, stream>>>(x, wq, wkv, wo, cx, cwq, cwkv, cwo);
    gemm_bias<<<dim3(DMODEL / 64, TSEQ / 64), 256, 0, stream>>>(
        cx, cwq, bq, qbuf, TSEQ, DMODEL, DMODEL);
    gemm_bias<<<dim3(512 / 64, TSEQ / 64), 256, 0, stream>>>(
        cx, cwkv, bkv, kvbuf, TSEQ, 512, DMODEL);
    norm_kernel<<<TSEQ, 256, 0, stream>>>(qbuf, kvbuf, qn_w, kn_w, qbf, kbf, vbuf);
    attn_kernel<<<NH * (TSEQ / 16), 64, 0, stream>>>(qbf, kbf, vbuf, ybuf);
    gemm_bias<<<dim3(DMODEL / 64, TSEQ / 64), 256, 0, stream>>>(
        ybuf, cwo, bo, out, TSEQ, DMODEL, DMODEL);
}

// Round 10
// 577.772 us; speedup vs baseline: 1.2241x; 1.0099x over previous
//
#include <hip/hip_runtime.h>
#include <hip/hip_bf16.h>
#include <stdint.h>

// Problem constants (fixed by reference)
#define TSEQ   2048
#define DMODEL 1024
#define NH     16
#define HDIM   64
#define NKVH   4

typedef __attribute__((ext_vector_type(8))) short short8;
typedef __attribute__((ext_vector_type(4))) float f32x4;
typedef __hip_bfloat16 bf16;

// priority comparator: higher score wins; tie -> lower index wins (matches jax top_k)
__device__ __forceinline__ bool pgt(float as, int ai, float bs, int bi) {
    return (as > bs) || (as == bs && ai < bi);
}

// full bitonic sort across 64 lanes, ascending by priority (validated R6/R7)
__device__ __forceinline__ void bsort(float& s, int& i, int lane) {
#pragma unroll
    for (int k = 2; k <= 64; k <<= 1) {
#pragma unroll
        for (int j = k >> 1; j > 0; j >>= 1) {
            float os = __shfl_xor(s, j, 64);
            int   oi = __shfl_xor(i, j, 64);
            bool lower = (lane & j) == 0;
            bool asc   = (lane & k) == 0;
            bool wmin  = (lower == asc);
            bool takeo = (pgt(s, i, os, oi) == wmin);
            if (takeo) { s = os; i = oi; }
        }
    }
}

// bitonic -> ascending cleanup (6 stages) (validated R6/R7)
__device__ __forceinline__ void bmerge(float& s, int& i, int lane) {
#pragma unroll
    for (int j = 32; j > 0; j >>= 1) {
        float os = __shfl_xor(s, j, 64);
        int   oi = __shfl_xor(i, j, 64);
        bool lower = (lane & j) == 0;
        bool takeo = (pgt(s, i, os, oi) == lower);
        if (takeo) { s = os; i = oi; }
    }
}

struct Sel { float s; int i; };

// merge one unsorted 64-candidate chunk into the sorted kept set.
// noinline (single I-cache copy) but BY VALUE: state stays in VGPRs. (R9)
__device__ __attribute__((noinline)) Sel merge_sel(Sel cur, float s, int j, int lane) {
    float nsv = s; int niv = j;
    bsort(nsv, niv, lane);
    float rsv = __shfl_xor(nsv, 63, 64);   // descending view of new chunk
    int   riv = __shfl_xor(niv, 63, 64);
    if (pgt(rsv, riv, cur.s, cur.i)) { cur.s = rsv; cur.i = riv; }
    bmerge(cur.s, cur.i, lane);            // restore ascending
    return cur;
}

// ---- fp32 -> bf16 conversion of x, wq, wkv, wo ----
__global__ __launch_bounds__(256) void convert_bf16(
    const float* __restrict__ x, const float* __restrict__ wq,
    const float* __restrict__ wkv, const float* __restrict__ wo,
    bf16* __restrict__ cx, bf16* __restrict__ cwq,
    bf16* __restrict__ cwkv, bf16* __restrict__ cwo)
{
    const size_t i0 = (size_t)blockIdx.x * 256 + threadIdx.x;
    const size_t stride = (size_t)gridDim.x * 256;
    for (size_t i = i0; i < 2097152; i += stride) cx[i]   = __float2bfloat16(x[i]);
    for (size_t i = i0; i < 1048576; i += stride) cwq[i]  = __float2bfloat16(wq[i]);
    for (size_t i = i0; i < 524288;  i += stride) cwkv[i] = __float2bfloat16(wkv[i]);
    for (size_t i = i0; i < 1048576; i += stride) cwo[i]  = __float2bfloat16(wo[i]);
}

// ---- MFMA GEMM: C[M,N] fp32 = A[M,K](bf16) @ B[K,N](bf16) + bias[N](fp32)
// 64x64 tile, 4 waves, mfma 16x16x32. (validated R7)
__global__ __launch_bounds__(256) void gemm_bias(
    const bf16* __restrict__ A, const bf16* __restrict__ B,
    const float* __restrict__ bias, float* __restrict__ C,
    int M, int N, int K)
{
    __shared__ short As[64][32];   // (m, k)
    __shared__ short Bt[64][32];   // (n, k)
    const int tid = threadIdx.x;
    const int m0 = blockIdx.y * 64, n0 = blockIdx.x * 64;
    const int w = tid >> 6, lane = tid & 63;
    const int q = lane >> 4, mm = lane & 15;
    f32x4 acc[4];
#pragma unroll
    for (int nb = 0; nb < 4; ++nb) acc[nb] = (f32x4){0.f, 0.f, 0.f, 0.f};
    const int arow = tid >> 2, akc = (tid & 3) * 8;
    const int brow = tid >> 3, bnc = (tid & 7) * 8;
    const short* Ag = (const short*)A;
    const short* Bg = (const short*)B;
    for (int k0 = 0; k0 < K; k0 += 32) {
        __syncthreads();
        short8 av = *(const short8*)(Ag + (size_t)(m0 + arow) * K + k0 + akc);
        *(short8*)(&As[arow][akc]) = av;
        short8 bv = *(const short8*)(Bg + (size_t)(k0 + brow) * N + n0 + bnc);
#pragma unroll
        for (int jj = 0; jj < 8; ++jj) Bt[bnc + jj][brow] = bv[jj];
        __syncthreads();
        short8 af = *(const short8*)(&As[w * 16 + mm][q * 8]);
#pragma unroll
        for (int nb = 0; nb < 4; ++nb) {
            short8 bfr = *(const short8*)(&Bt[nb * 16 + mm][q * 8]);
            acc[nb] = __builtin_amdgcn_mfma_f32_16x16x32_bf16(af, bfr, acc[nb], 0, 0, 0);
        }
    }
#pragma unroll
    for (int nb = 0; nb < 4; ++nb) {
#pragma unroll
        for (int r = 0; r < 4; ++r) {
            int row = m0 + w * 16 + q * 4 + r;
            int col = n0 + nb * 16 + mm;
            C[(size_t)row * N + col] = acc[nb][r] + bias[col];
        }
    }
}

// ---- RMSNorm q and k -> bf16 tiles; V stays fp32 ---- (validated R8)
__global__ __launch_bounds__(256) void norm_kernel(
    const float* __restrict__ qbuf, const float* __restrict__ kvbuf,
    const float* __restrict__ qn_w, const float* __restrict__ kn_w,
    bf16* __restrict__ qbf, bf16* __restrict__ kbf, float* __restrict__ vbuf)
{
    const int t = blockIdx.x;
    const int tid = threadIdx.x;
#pragma unroll
    for (int it = 0; it < 6; ++it) {
        int idx = it * 256 + tid;
        int chunk = idx >> 6;        // 0..15 q heads, 16..19 k kvh, 20..23 v kvh
        int d = idx & 63;
        float val;
        if (chunk < 16)      val = qbuf[(size_t)t * DMODEL + chunk * 64 + d];
        else if (chunk < 20) val = kvbuf[(size_t)t * 512 + (chunk - 16) * 64 + d];
        else                 val = kvbuf[(size_t)t * 512 + 256 + (chunk - 20) * 64 + d];
        if (chunk < 20) {
            float ss = val * val;
#pragma unroll
            for (int j = 32; j > 0; j >>= 1) ss += __shfl_xor(ss, j, 64);
            float rs = 1.0f / sqrtf(ss * (1.0f / 64.0f) + 1e-8f);
            if (chunk < 16) {
                qbf[(size_t)t * DMODEL + chunk * 64 + d] =
                    __float2bfloat16(val * rs * qn_w[d]);
            } else {
                int kvh = chunk - 16;
                kbf[((size_t)kvh * TSEQ + t) * HDIM + d] =
                    __float2bfloat16(val * rs * kn_w[d]);
            }
        } else {
            int kvh = chunk - 20;
            vbuf[((size_t)kvh * TSEQ + t) * HDIM + d] = val;
        }
    }
}

// ---- MFMA-scored fused attention, 4 waves per (h, 16-query tile) ----
// Wave w scans chunks {cmax-w, cmax-w-4, ...} with the R9-proven inner loop
// (reg-resident top-64 per query). Final: the 4 sorted sets are merged via
// LDS with 3 sorted bitonic merges (top64(A∪B) = elementwise pgt-max of
// ascending A vs reversed B, then bmerge). Each wave runs the epilogue for
// 4 queries.
__global__ __launch_bounds__(256) void attn_kernel(
    const bf16* __restrict__ qbf, const bf16* __restrict__ kbf,
    const float* __restrict__ vbuf, bf16* __restrict__ ybuf)
{
    __shared__ __align__(16) char shraw[32768];
    const int tid = threadIdx.x;
    const int w = tid >> 6, lane = tid & 63;
    const int h  = blockIdx.x & 15;
    const int qt = 127 - (blockIdx.x >> 4);   // heavy tiles dispatch first
    const int t0 = qt * 16;
    const int kvh = h >> 2;
    const float slope = exp2f(-(((float)h / 15.0f) * 8.0f));
    const int mm = lane & 15, quad = lane >> 4;
    float* Ss = (float*)shraw + w * (16 * 68);   // wave-private [16][68]

    // A-frags: Q[m = t0+mm][k] halves k0=0,32 (gemm-proven layout)
    const short* qg = (const short*)qbf + (size_t)h * 64;
    short8 af0 = *(const short8*)(qg + (size_t)(t0 + mm) * DMODEL + quad * 8);
    short8 af1 = *(const short8*)(qg + (size_t)(t0 + mm) * DMODEL + 32 + quad * 8);
    const short* kg = (const short*)kbf + (size_t)kvh * TSEQ * HDIM;

    float cs[16]; int ci[16];
#pragma unroll
    for (int i = 0; i < 16; ++i) { cs[i] = -1e30f; ci[i] = 0; }

    const int cmax = (t0 + 15) >> 6;
    bool first = true;
    for (int c = cmax - w; c >= 0; c -= 4) {
        const int jb = c << 6;
#pragma unroll
        for (int kb = 0; kb < 4; ++kb) {
            const short* kr = kg + (size_t)(jb + kb * 16 + mm) * HDIM;
            short8 b0 = *(const short8*)(kr + quad * 8);
            short8 b1 = *(const short8*)(kr + 32 + quad * 8);
            f32x4 acc = (f32x4){0.f, 0.f, 0.f, 0.f};
            acc = __builtin_amdgcn_mfma_f32_16x16x32_bf16(af0, b0, acc, 0, 0, 0);
            acc = __builtin_amdgcn_mfma_f32_16x16x32_bf16(af1, b1, acc, 0, 0, 0);
            const int jj = jb + kb * 16 + mm;
#pragma unroll
            for (int r = 0; r < 4; ++r) {
                int qq = quad * 4 + r;
                int tt = t0 + qq;
                float s = (jj <= tt) ? (acc[r] * 0.125f - slope * (float)(tt - jj))
                                     : -1e30f;
                Ss[qq * 68 + kb * 16 + mm] = s;
            }
        }
        if (first) {
            first = false;
#pragma unroll
            for (int i = 0; i < 16; ++i) {
                cs[i] = Ss[i * 68 + lane]; ci[i] = jb + lane;
                bsort(cs[i], ci[i], lane);
            }
        } else {
#pragma unroll
            for (int i = 0; i < 16; ++i) {
                float s = Ss[i * 68 + lane];
                float th = __shfl(cs[i], 0, 64);   // current 64th-largest
                if (__any(s >= th)) {
                    Sel st{cs[i], ci[i]};
                    st = merge_sel(st, s, jb + lane, lane);
                    cs[i] = st.s; ci[i] = st.i;
                }
            }
        }
    }

    // publish sorted sets, then tree-merge (reuses Ss region; barriers order it)
    __syncthreads();
    float* Ms = (float*)shraw;             // [4][16][64] scores
    int*   Mi = (int*)(shraw + 16384);     // [4][16][64] indices
#pragma unroll
    for (int i = 0; i < 16; ++i) {
        Ms[(w * 16 + i) * 64 + lane] = cs[i];
        Mi[(w * 16 + i) * 64 + lane] = ci[i];
    }
    __syncthreads();

    // wave w owns queries q = 4w..4w+3: merge 4 sorted sets, then epilogue
    const float* vb = vbuf + (size_t)kvh * TSEQ * HDIM + lane;
    for (int e = 0; e < 4; ++e) {
        const int q = w * 4 + e;
        float cur_s = Ms[(0 * 16 + q) * 64 + lane];
        int   cur_i = Mi[(0 * 16 + q) * 64 + lane];
        for (int w2 = 1; w2 < 4; ++w2) {
            float os = Ms[(w2 * 16 + q) * 64 + (63 - lane)];  // descending view
            int   oi = Mi[(w2 * 16 + q) * 64 + (63 - lane)];
            if (pgt(os, oi, cur_s, cur_i)) { cur_s = os; cur_i = oi; }
            bmerge(cur_s, cur_i, lane);
        }
        // softmax + V gather (R7-proven)
        float msx = __shfl(cur_s, 63, 64);
        bool valid = cur_s > -1e29f;
        float p = valid ? __expf(cur_s - msx) : 0.f;
        float l = p;
#pragma unroll
        for (int j2 = 32; j2 > 0; j2 >>= 1) l += __shfl_xor(l, j2, 64);
        float wgt = p / l;
        int widx = valid ? cur_i : 0;
        float acc = 0.f;
#pragma unroll 8
        for (int u = 0; u < 64; ++u) {
            float ww = __shfl(wgt, u, 64);
            int  ix = __shfl(widx, u, 64);
            acc += ww * vb[(size_t)ix * HDIM];
        }
        int tt = t0 + q;
        ybuf[(size_t)tt * DMODEL + h * 64 + lane] = __float2bfloat16(acc);
    }
}

extern "C" void kernel_launch(void* const* d_in, const int* in_sizes, int n_in,
                              void* d_out, int out_size, void* d_ws, size_t ws_size,
                              hipStream_t stream)
{
    // d_in order: x, wq, bq, wkv, bkv, wo, bo, qn_w, kn_w  (all fp32)
    const float* x    = (const float*)d_in[0];
    const float* wq   = (const float*)d_in[1];
    const float* bq   = (const float*)d_in[2];
    const float* wkv  = (const float*)d_in[3];
    const float* bkv  = (const float*)d_in[4];
    const float* wo   = (const float*)d_in[5];
    const float* bo   = (const float*)d_in[6];
    const float* qn_w = (const float*)d_in[7];
    const float* kn_w = (const float*)d_in[8];
    char* ws = (char*)d_ws;
    // ws layout (28 MB):
    // cx bf16 4M @0 | cwq 2M @4M | cwkv 1M @6M | cwo 2M @7M |
    // qbuf fp32 8M @9M (reused as ybuf bf16 after norm) | kvbuf fp32 4M @17M |
    // qbf bf16 4M @21M | kbf bf16 1M @25M | vbuf fp32 2M @26M
    bf16*  cx    = (bf16*)(ws);
    bf16*  cwq   = (bf16*)(ws + ((size_t)4  << 20));
    bf16*  cwkv  = (bf16*)(ws + ((size_t)6  << 20));
    bf16*  cwo   = (bf16*)(ws + ((size_t)7  << 20));
    float* qbuf  = (float*)(ws + ((size_t)9  << 20));
    bf16*  ybuf  = (bf16*)(ws + ((size_t)9  << 20));   // aliases qbuf (dead after norm)
    float* kvbuf = (float*)(ws + ((size_t)17 << 20));
    bf16*  qbf   = (bf16*)(ws + ((size_t)21 << 20));
    bf16*  kbf   = (bf16*)(ws + ((size_t)25 << 20));
    float* vbuf  = (float*)(ws + ((size_t)26 << 20));
    float* out   = (float*)d_out;   // fp32 output

    convert_bf16<<<2048, 256, 0, stream>>>(x, wq, wkv, wo, cx, cwq, cwkv, cwo);
    gemm_bias<<<dim3(DMODEL / 64, TSEQ / 64), 256, 0, stream>>>(
        cx, cwq, bq, qbuf, TSEQ, DMODEL, DMODEL);
    gemm_bias<<<dim3(512 / 64, TSEQ / 64), 256, 0, stream>>>(
        cx, cwkv, bkv, kvbuf, TSEQ, 512, DMODEL);
    norm_kernel<<<TSEQ, 256, 0, stream>>>(qbuf, kvbuf, qn_w, kn_w, qbf, kbf, vbuf);
    attn_kernel<<<NH * (TSEQ / 16), 256, 0, stream>>>(qbf, kbf, vbuf, ybuf);
    gemm_bias<<<dim3(DMODEL / 64, TSEQ / 64), 256, 0, stream>>>(
        ybuf, cwo, bo, out, TSEQ, DMODEL, DMODEL);
}